// Round 8
// baseline (120.650 us; speedup 1.0000x reference)
//
#include <hip/hip_runtime.h>

#define BB 256
#define TT 1024
#define VV 64
#define LL 64
#define LOG2E 1.4426950408889634f
#define LN2   0.6931471805599453f

__device__ __forceinline__ int   f2i(float x) { return __float_as_int(x); }
__device__ __forceinline__ float i2f(int x)   { return __int_as_float(x); }

// wave-wide max of non-negative values (0 identity), result broadcast
__device__ __forceinline__ float wave_max63(float x) {
  x = fmaxf(x, i2f(__builtin_amdgcn_update_dpp(0, f2i(x), 0x111, 0xF, 0xF, true)));
  x = fmaxf(x, i2f(__builtin_amdgcn_update_dpp(0, f2i(x), 0x112, 0xF, 0xF, true)));
  x = fmaxf(x, i2f(__builtin_amdgcn_update_dpp(0, f2i(x), 0x114, 0xF, 0xF, true)));
  x = fmaxf(x, i2f(__builtin_amdgcn_update_dpp(0, f2i(x), 0x118, 0xF, 0xF, true)));
  x = fmaxf(x, i2f(__builtin_amdgcn_update_dpp(0, f2i(x), 0x142, 0xF, 0xF, true)));
  x = fmaxf(x, i2f(__builtin_amdgcn_update_dpp(0, f2i(x), 0x143, 0xF, 0xF, true)));
  return i2f(__builtin_amdgcn_readlane(f2i(x), 63));
}

// ---------- R8: R7 fwd/bwd DP (unchanged) + direction-split deep-pipelined LSE ----------
// R7 gained only 10% from halving the DP chain: the bwd DP wave gathers rows
// DESCENDING from len-1 -- rows the forward-streaming LSE waves hadn't warmed,
// so it paid cold-HBM latency (~900cy) per window with only ~800cy lookahead.
// R8: LSE waves 2-3 stream [0,mid) ascending (warm L2/L3 ahead of fwd DP);
// waves 4-5 stream [len-1,mid] DESCENDING (warm ahead of bwd DP). LSE register
// pipeline deepened 3->8 (8-set rotation, 2 float4/body): ~1000cy coverage >=
// HBM latency, so the warmers run at BW. Over-run bodies use clamped addrs +
// row guards (all reg indices static). DP math is byte-identical to R7
// (renorm 2^60, RESCALE45 combine, p-clamp); lsePart is only reassociated.
extern "C" __global__ void __launch_bounds__(384, 1)
ctc_fused(const int* __restrict__ labels, const float* __restrict__ logits,
          const int* __restrict__ mask, float* __restrict__ out) {
  __shared__ float lsePart[4];
  __shared__ float sG0v[64], sG1v[64];
  __shared__ float sG2s;
  __shared__ int   sCtB;
  const int b = blockIdx.x;
  const int tid = threadIdx.x;
  const int lane = tid & 63;
  const int wv = tid >> 6;

  const float* lg = logits + (size_t)b * TT * VV;

  // every wave computes len (redundant, preamble-only)
  int lsum = 0;
  const int* mrow = mask + b * TT;
#pragma unroll
  for (int k = 0; k < TT / 64; ++k) lsum += mrow[lane + (k << 6)];
#pragma unroll
  for (int off = 32; off; off >>= 1) lsum += __shfl_xor(lsum, off);
  int len = __builtin_amdgcn_readfirstlane(lsum);
  len = len < 1 ? 1 : (len > TT ? TT : len);
  int mid = len >> 1; mid = mid < 1 ? 1 : mid;
  const int nwF = (mid + 15) >> 4;           // forward DP windows: rows [0, mid)
  const int nwB = (len - mid + 15) >> 4;     // backward DP windows: rows [len-1, mid]

  // forward state (wave 0 only; top-level for the epilogue)
  int lab_len = 0;
  float A0 = 0.0f, A1 = 0.0f, A2 = 0.0f;
  int ctotA = 0;

#define RENORM3(X, Y, Z, CT) { \
    const float mxv = wave_max63(fmaxf(fmaxf(X, Y), Z)); \
    const int eb_ = (f2i(mxv) >> 23) & 255; \
    int kk = (eb_ > 0 && eb_ < 255) ? (187 - eb_) : 0; \
    kk = kk > 126 ? 126 : (kk < -126 ? -126 : kk); \
    CT += kk; \
    const float sc = i2f((127 + kk) << 23); \
    X *= sc; Y *= sc; Z *= sc; \
  }

  // final rescale to 2^45: keeps the cross-wave product within fp32 range
#define RESCALE45(X, Y, Z, CT) { \
    const float mxv = wave_max63(fmaxf(fmaxf(X, Y), Z)); \
    const int eb_ = (f2i(mxv) >> 23) & 255; \
    int kk = (eb_ > 0 && eb_ < 255) ? (172 - eb_) : 0; \
    kk = kk > 126 ? 126 : (kk < -126 ? -126 : kk); \
    CT += kk; \
    const float sc = i2f((127 + kk) << 23); \
    X *= sc; Y *= sc; Z *= sc; \
  }

  if (wv == 0) {
    // ================= forward DP wave: rows [0, mid) =================
    const int lab = labels[b * LL + lane] & 63;   // label for state 2*lane+1
    lab_len = (int)__popcll(__ballot(lab != 0));
    const int plab = __builtin_amdgcn_update_dpp(0, lab, 0x138, 0xF, 0xF, false);
    const float sk = (lab != 0 && lab != plab) ? 1.0f : 0.0f; // allow_skip
    A0 = (lane == 0) ? 1.0f : 0.0f;               // t=0 runs as a normal step
    __builtin_amdgcn_s_setprio(1);

    const int cu = lane & 15;
    const float* lgg = lg + lab;                  // per-lane gather base
    const float* lgc = lg + (cu << 6);            // lane u<16 -> row u, col 0

    float qa_c, qb_c, qc_c;
    float qa_g0, qa_g1, qa_g2, qa_g3, qa_g4, qa_g5, qa_g6, qa_g7,
          qa_g8, qa_g9, qa_g10, qa_g11, qa_g12, qa_g13, qa_g14, qa_g15;
    float qb_g0, qb_g1, qb_g2, qb_g3, qb_g4, qb_g5, qb_g6, qb_g7,
          qb_g8, qb_g9, qb_g10, qb_g11, qb_g12, qb_g13, qb_g14, qb_g15;
    float qc_g0, qc_g1, qc_g2, qc_g3, qc_g4, qc_g5, qc_g6, qc_g7,
          qc_g8, qc_g9, qc_g10, qc_g11, qc_g12, qc_g13, qc_g14, qc_g15;

#define FISSUE(WN, S) { \
    const float* pg_ = lgg + ((WN) << 10); \
    S##_g0  = pg_[0];    S##_g1  = pg_[64];   S##_g2  = pg_[128];  S##_g3  = pg_[192]; \
    S##_g4  = pg_[256];  S##_g5  = pg_[320];  S##_g6  = pg_[384];  S##_g7  = pg_[448]; \
    S##_g8  = pg_[512];  S##_g9  = pg_[576];  S##_g10 = pg_[640];  S##_g11 = pg_[704]; \
    S##_g12 = pg_[768];  S##_g13 = pg_[832];  S##_g14 = pg_[896];  S##_g15 = pg_[960]; \
    S##_c = lgc[(WN) << 10]; \
  }

#define FSTEPU(U) { \
    const float A1p = i2f(__builtin_amdgcn_update_dpp(0, f2i(A1), 0x138, 0xF, 0xF, false)); \
    const float nA0 = c##U * (A0 + A1p); \
    const float nA1 = g##U * fmaf(sk, A1p, A0 + A1); \
    A2 = c##U * (A2 + A1); \
    A0 = nA0; A1 = nA1; \
  }

#define FSTEPM(U) { \
    const float A1p = i2f(__builtin_amdgcn_update_dpp(0, f2i(A1), 0x138, 0xF, 0xF, false)); \
    const float nA0 = c##U * (A0 + A1p); \
    const float nA1 = g##U * fmaf(sk, A1p, A0 + A1); \
    const float nA2 = c##U * (A2 + A1); \
    const bool act = (tbase + (U)) < mid; \
    A0 = act ? nA0 : A0; A1 = act ? nA1 : A1; A2 = act ? nA2 : A2; \
  }

#define FBODY(W, S) { \
    const float cv = __builtin_amdgcn_exp2f(S##_c * LOG2E); \
    const float g0  = __builtin_amdgcn_exp2f(S##_g0  * LOG2E); \
    const float g1  = __builtin_amdgcn_exp2f(S##_g1  * LOG2E); \
    const float g2  = __builtin_amdgcn_exp2f(S##_g2  * LOG2E); \
    const float g3  = __builtin_amdgcn_exp2f(S##_g3  * LOG2E); \
    const float g4  = __builtin_amdgcn_exp2f(S##_g4  * LOG2E); \
    const float g5  = __builtin_amdgcn_exp2f(S##_g5  * LOG2E); \
    const float g6  = __builtin_amdgcn_exp2f(S##_g6  * LOG2E); \
    const float g7  = __builtin_amdgcn_exp2f(S##_g7  * LOG2E); \
    const float g8  = __builtin_amdgcn_exp2f(S##_g8  * LOG2E); \
    const float g9  = __builtin_amdgcn_exp2f(S##_g9  * LOG2E); \
    const float g10 = __builtin_amdgcn_exp2f(S##_g10 * LOG2E); \
    const float g11 = __builtin_amdgcn_exp2f(S##_g11 * LOG2E); \
    const float g12 = __builtin_amdgcn_exp2f(S##_g12 * LOG2E); \
    const float g13 = __builtin_amdgcn_exp2f(S##_g13 * LOG2E); \
    const float g14 = __builtin_amdgcn_exp2f(S##_g14 * LOG2E); \
    const float g15 = __builtin_amdgcn_exp2f(S##_g15 * LOG2E); \
    if ((W) + 3 < 64) { FISSUE((W) + 3, S) } \
    const float c0  = i2f(__builtin_amdgcn_readlane(f2i(cv), 0)); \
    const float c1  = i2f(__builtin_amdgcn_readlane(f2i(cv), 1)); \
    const float c2  = i2f(__builtin_amdgcn_readlane(f2i(cv), 2)); \
    const float c3  = i2f(__builtin_amdgcn_readlane(f2i(cv), 3)); \
    const float c4  = i2f(__builtin_amdgcn_readlane(f2i(cv), 4)); \
    const float c5  = i2f(__builtin_amdgcn_readlane(f2i(cv), 5)); \
    const float c6  = i2f(__builtin_amdgcn_readlane(f2i(cv), 6)); \
    const float c7  = i2f(__builtin_amdgcn_readlane(f2i(cv), 7)); \
    const float c8  = i2f(__builtin_amdgcn_readlane(f2i(cv), 8)); \
    const float c9  = i2f(__builtin_amdgcn_readlane(f2i(cv), 9)); \
    const float c10 = i2f(__builtin_amdgcn_readlane(f2i(cv), 10)); \
    const float c11 = i2f(__builtin_amdgcn_readlane(f2i(cv), 11)); \
    const float c12 = i2f(__builtin_amdgcn_readlane(f2i(cv), 12)); \
    const float c13 = i2f(__builtin_amdgcn_readlane(f2i(cv), 13)); \
    const float c14 = i2f(__builtin_amdgcn_readlane(f2i(cv), 14)); \
    const float c15 = i2f(__builtin_amdgcn_readlane(f2i(cv), 15)); \
    RENORM3(A0, A1, A2, ctotA) \
    const int tbase = (W) << 4; \
    if (tbase + 16 <= mid) { \
      FSTEPU(0)  FSTEPU(1)  FSTEPU(2)  FSTEPU(3)  FSTEPU(4)  FSTEPU(5)  FSTEPU(6)  FSTEPU(7) \
      FSTEPU(8)  FSTEPU(9)  FSTEPU(10) FSTEPU(11) FSTEPU(12) FSTEPU(13) FSTEPU(14) FSTEPU(15) \
    } else { \
      FSTEPM(0)  FSTEPM(1)  FSTEPM(2)  FSTEPM(3)  FSTEPM(4)  FSTEPM(5)  FSTEPM(6)  FSTEPM(7) \
      FSTEPM(8)  FSTEPM(9)  FSTEPM(10) FSTEPM(11) FSTEPM(12) FSTEPM(13) FSTEPM(14) FSTEPM(15) \
    } \
  }

    FISSUE(0, qa) FISSUE(1, qb) FISSUE(2, qc)
    int w = 0;
    for (; w + 3 <= nwF; w += 3) {
      FBODY(w, qa) FBODY(w + 1, qb) FBODY(w + 2, qc)
    }
    if (w < nwF) { FBODY(w, qa) ++w; }
    if (w < nwF) { FBODY(w, qb) ++w; }
#undef FBODY
#undef FSTEPM
#undef FSTEPU
#undef FISSUE
    RESCALE45(A0, A1, A2, ctotA)

  } else if (wv == 1) {
    // ================= backward (suffix) DP wave: rows [len-1, mid] =================
    const int lab = labels[b * LL + lane] & 63;
    const int ll = (int)__popcll(__ballot(lab != 0));
    const int plab = __builtin_amdgcn_update_dpp(0, lab, 0x138, 0xF, 0xF, false);
    const float sk = (lab != 0 && lab != plab) ? 1.0f : 0.0f;
    const float skp = i2f(__builtin_amdgcn_update_dpp(0, f2i(sk), 0x130, 0xF, 0xF, false)); // sk[l+1]
    const bool is63 = (lane == 63);
    __builtin_amdgcn_s_setprio(1);

    // gamma seeds at t = len: [s==e] + [s==max(e-1,0)], e = 2*ll
    float G0 = 0.0f, G1 = 0.0f, G2 = 0.0f;
    if (ll == 0)            { G0 = (lane == 0) ? 2.0f : 0.0f; }
    else if (ll >= LL)      { G2 = 1.0f; G1 = is63 ? 1.0f : 0.0f; }
    else {
      G0 = (lane == ll) ? 1.0f : 0.0f;
      G1 = (lane == ll - 1) ? 1.0f : 0.0f;
    }
    int ctotB = 0;

    const int cu = lane & 15;
    const float* lgg = lg + lab;

    float ra_c, rb_c, rc_c;
    float ra_g0, ra_g1, ra_g2, ra_g3, ra_g4, ra_g5, ra_g6, ra_g7,
          ra_g8, ra_g9, ra_g10, ra_g11, ra_g12, ra_g13, ra_g14, ra_g15;
    float rb_g0, rb_g1, rb_g2, rb_g3, rb_g4, rb_g5, rb_g6, rb_g7,
          rb_g8, rb_g9, rb_g10, rb_g11, rb_g12, rb_g13, rb_g14, rb_g15;
    float rc_g0, rc_g1, rc_g2, rc_g3, rc_g4, rc_g5, rc_g6, rc_g7,
          rc_g8, rc_g9, rc_g10, rc_g11, rc_g12, rc_g13, rc_g14, rc_g15;

#define BLD(RW) ( (RW) < 0 ? 0 : (RW) )
#define BISSUE(J, S) { \
    const int br_ = len - 1 - ((J) << 4); \
    S##_g0  = lgg[BLD(br_ - 0)  << 6]; S##_g1  = lgg[BLD(br_ - 1)  << 6]; \
    S##_g2  = lgg[BLD(br_ - 2)  << 6]; S##_g3  = lgg[BLD(br_ - 3)  << 6]; \
    S##_g4  = lgg[BLD(br_ - 4)  << 6]; S##_g5  = lgg[BLD(br_ - 5)  << 6]; \
    S##_g6  = lgg[BLD(br_ - 6)  << 6]; S##_g7  = lgg[BLD(br_ - 7)  << 6]; \
    S##_g8  = lgg[BLD(br_ - 8)  << 6]; S##_g9  = lgg[BLD(br_ - 9)  << 6]; \
    S##_g10 = lgg[BLD(br_ - 10) << 6]; S##_g11 = lgg[BLD(br_ - 11) << 6]; \
    S##_g12 = lgg[BLD(br_ - 12) << 6]; S##_g13 = lgg[BLD(br_ - 13) << 6]; \
    S##_g14 = lgg[BLD(br_ - 14) << 6]; S##_g15 = lgg[BLD(br_ - 15) << 6]; \
    S##_c = lg[BLD(br_ - cu) << 6]; \
  }

#define BSTEPU(U) { \
    const float V_ = i2f(__builtin_amdgcn_update_dpp(0, f2i(G1), 0x130, 0xF, 0xF, false)); \
    float U_ = i2f(__builtin_amdgcn_update_dpp(0, f2i(G0), 0x130, 0xF, 0xF, false)); \
    U_ = is63 ? G2 : U_; \
    const float nG0 = fmaf(cB##U, G0, gB##U * G1); \
    const float nG1 = fmaf(gB##U, G1, fmaf(cB##U, U_, hB##U * V_)); \
    G2 = cB##U * G2; \
    G0 = nG0; G1 = nG1; \
  }

#define BSTEPM(U) { \
    const float V_ = i2f(__builtin_amdgcn_update_dpp(0, f2i(G1), 0x130, 0xF, 0xF, false)); \
    float U_ = i2f(__builtin_amdgcn_update_dpp(0, f2i(G0), 0x130, 0xF, 0xF, false)); \
    U_ = is63 ? G2 : U_; \
    const float nG0 = fmaf(cB##U, G0, gB##U * G1); \
    const float nG1 = fmaf(gB##U, G1, fmaf(cB##U, U_, hB##U * V_)); \
    const float nG2 = cB##U * G2; \
    const bool act = (brow0 - (U)) >= mid; \
    G0 = act ? nG0 : G0; G1 = act ? nG1 : G1; G2 = act ? nG2 : G2; \
  }

#define BPREP(U, S) \
    const float gB##U = __builtin_amdgcn_exp2f(S##_g##U * LOG2E); \
    const float hB##U = skp * i2f(__builtin_amdgcn_update_dpp(0, f2i(gB##U), 0x130, 0xF, 0xF, false));

#define BBODY(J, S) { \
    const int brow0 = len - 1 - ((J) << 4); \
    const float cv = __builtin_amdgcn_exp2f(S##_c * LOG2E); \
    BPREP(0, S)  BPREP(1, S)  BPREP(2, S)  BPREP(3, S) \
    BPREP(4, S)  BPREP(5, S)  BPREP(6, S)  BPREP(7, S) \
    BPREP(8, S)  BPREP(9, S)  BPREP(10, S) BPREP(11, S) \
    BPREP(12, S) BPREP(13, S) BPREP(14, S) BPREP(15, S) \
    if ((J) + 3 < 64) { BISSUE((J) + 3, S) } \
    const float cB0  = i2f(__builtin_amdgcn_readlane(f2i(cv), 0)); \
    const float cB1  = i2f(__builtin_amdgcn_readlane(f2i(cv), 1)); \
    const float cB2  = i2f(__builtin_amdgcn_readlane(f2i(cv), 2)); \
    const float cB3  = i2f(__builtin_amdgcn_readlane(f2i(cv), 3)); \
    const float cB4  = i2f(__builtin_amdgcn_readlane(f2i(cv), 4)); \
    const float cB5  = i2f(__builtin_amdgcn_readlane(f2i(cv), 5)); \
    const float cB6  = i2f(__builtin_amdgcn_readlane(f2i(cv), 6)); \
    const float cB7  = i2f(__builtin_amdgcn_readlane(f2i(cv), 7)); \
    const float cB8  = i2f(__builtin_amdgcn_readlane(f2i(cv), 8)); \
    const float cB9  = i2f(__builtin_amdgcn_readlane(f2i(cv), 9)); \
    const float cB10 = i2f(__builtin_amdgcn_readlane(f2i(cv), 10)); \
    const float cB11 = i2f(__builtin_amdgcn_readlane(f2i(cv), 11)); \
    const float cB12 = i2f(__builtin_amdgcn_readlane(f2i(cv), 12)); \
    const float cB13 = i2f(__builtin_amdgcn_readlane(f2i(cv), 13)); \
    const float cB14 = i2f(__builtin_amdgcn_readlane(f2i(cv), 14)); \
    const float cB15 = i2f(__builtin_amdgcn_readlane(f2i(cv), 15)); \
    RENORM3(G0, G1, G2, ctotB) \
    if (brow0 - 15 >= mid) { \
      BSTEPU(0)  BSTEPU(1)  BSTEPU(2)  BSTEPU(3)  BSTEPU(4)  BSTEPU(5)  BSTEPU(6)  BSTEPU(7) \
      BSTEPU(8)  BSTEPU(9)  BSTEPU(10) BSTEPU(11) BSTEPU(12) BSTEPU(13) BSTEPU(14) BSTEPU(15) \
    } else { \
      BSTEPM(0)  BSTEPM(1)  BSTEPM(2)  BSTEPM(3)  BSTEPM(4)  BSTEPM(5)  BSTEPM(6)  BSTEPM(7) \
      BSTEPM(8)  BSTEPM(9)  BSTEPM(10) BSTEPM(11) BSTEPM(12) BSTEPM(13) BSTEPM(14) BSTEPM(15) \
    } \
  }

    BISSUE(0, ra) BISSUE(1, rb) BISSUE(2, rc)
    int j = 0;
    for (; j + 3 <= nwB; j += 3) {
      BBODY(j, ra) BBODY(j + 1, rb) BBODY(j + 2, rc)
    }
    if (j < nwB) { BBODY(j, ra) ++j; }
    if (j < nwB) { BBODY(j, rb) ++j; }
#undef BBODY
#undef BPREP
#undef BSTEPM
#undef BSTEPU
#undef BISSUE
#undef BLD
    RESCALE45(G0, G1, G2, ctotB)

    sG0v[lane] = G0;
    sG1v[lane] = G1;
    if (is63) sG2s = G2;
    if (lane == 0) sCtB = ctotB;

  } else {
    // ===== LSE waves: 2-3 ascending over [0,mid) (warm fwd DP); 4-5 descending
    // over [len-1,mid] (warm bwd DP). 8-set register rotation, 2 float4/body. =====
    const int q = lane >> 4;
    const int u15 = ((lane & 15) == 15);
    const int colv2 = (lane & 15) << 2;
    const int TTm1 = TT - 1;
    float acc = 0.0f;
    float4 e0A, e0B, e1A, e1B, e2A, e2B, e3A, e3B,
           e4A, e4B, e5A, e5B, e6A, e6B, e7A, e7B;

#define LSUM(V, S) \
    float S = (__builtin_amdgcn_exp2f((V).x * LOG2E) + __builtin_amdgcn_exp2f((V).y * LOG2E)) \
            + (__builtin_amdgcn_exp2f((V).z * LOG2E) + __builtin_amdgcn_exp2f((V).w * LOG2E)); \
    S += i2f(__builtin_amdgcn_update_dpp(0, f2i(S), 0x111, 0xF, 0xF, true)); \
    S += i2f(__builtin_amdgcn_update_dpp(0, f2i(S), 0x112, 0xF, 0xF, true)); \
    S += i2f(__builtin_amdgcn_update_dpp(0, f2i(S), 0x114, 0xF, 0xF, true)); \
    S += i2f(__builtin_amdgcn_update_dpp(0, f2i(S), 0x118, 0xF, 0xF, true));

    if (wv < 4) {
      const int f = wv - 2;
#define LFISSUE(K, SA, SB) { \
      int rA_ = ((K) << 4) + (f << 3) + q; \
      int rB_ = rA_ + 4; \
      rA_ = rA_ > TTm1 ? TTm1 : rA_; \
      rB_ = rB_ > TTm1 ? TTm1 : rB_; \
      SA = *(const float4*)(lg + (rA_ << 6) + colv2); \
      SB = *(const float4*)(lg + (rB_ << 6) + colv2); \
    }
#define LFBODY(K, SA, SB) { \
      const int rA_ = ((K) << 4) + (f << 3) + q; \
      const float4 vA_ = SA, vB_ = SB; \
      LFISSUE((K) + 8, SA, SB) \
      LSUM(vA_, sA_) \
      LSUM(vB_, sB_) \
      if (u15 && rA_ < mid) acc += __logf(sA_); \
      if (u15 && rA_ + 4 < mid) acc += __logf(sB_); \
    }
      const int nwl = (mid + 15) >> 4;
      const int NB8 = ((nwl + 7) >> 3) << 3;
      LFISSUE(0, e0A, e0B) LFISSUE(1, e1A, e1B) LFISSUE(2, e2A, e2B) LFISSUE(3, e3A, e3B)
      LFISSUE(4, e4A, e4B) LFISSUE(5, e5A, e5B) LFISSUE(6, e6A, e6B) LFISSUE(7, e7A, e7B)
      for (int k = 0; k < NB8; k += 8) {
        LFBODY(k + 0, e0A, e0B) LFBODY(k + 1, e1A, e1B)
        LFBODY(k + 2, e2A, e2B) LFBODY(k + 3, e3A, e3B)
        LFBODY(k + 4, e4A, e4B) LFBODY(k + 5, e5A, e5B)
        LFBODY(k + 6, e6A, e6B) LFBODY(k + 7, e7A, e7B)
      }
#undef LFBODY
#undef LFISSUE
    } else {
      const int bw = wv - 4;
#define LBISSUE(J, SA, SB) { \
      int rA_ = len - 1 - ((J) << 4) - (bw << 3) - q; \
      int rB_ = rA_ - 4; \
      rA_ = rA_ < 0 ? 0 : rA_; \
      rB_ = rB_ < 0 ? 0 : rB_; \
      SA = *(const float4*)(lg + (rA_ << 6) + colv2); \
      SB = *(const float4*)(lg + (rB_ << 6) + colv2); \
    }
#define LBBODY(J, SA, SB) { \
      const int rA_ = len - 1 - ((J) << 4) - (bw << 3) - q; \
      const float4 vA_ = SA, vB_ = SB; \
      LBISSUE((J) + 8, SA, SB) \
      LSUM(vA_, sA_) \
      LSUM(vB_, sB_) \
      if (u15 && rA_ >= mid) acc += __logf(sA_); \
      if (u15 && rA_ - 4 >= mid) acc += __logf(sB_); \
    }
      const int nwl = (len - mid + 15) >> 4;
      const int NB8 = ((nwl + 7) >> 3) << 3;
      LBISSUE(0, e0A, e0B) LBISSUE(1, e1A, e1B) LBISSUE(2, e2A, e2B) LBISSUE(3, e3A, e3B)
      LBISSUE(4, e4A, e4B) LBISSUE(5, e5A, e5B) LBISSUE(6, e6A, e6B) LBISSUE(7, e7A, e7B)
      for (int j = 0; j < NB8; j += 8) {
        LBBODY(j + 0, e0A, e0B) LBBODY(j + 1, e1A, e1B)
        LBBODY(j + 2, e2A, e2B) LBBODY(j + 3, e3A, e3B)
        LBBODY(j + 4, e4A, e4B) LBBODY(j + 5, e5A, e5B)
        LBBODY(j + 6, e6A, e6B) LBBODY(j + 7, e7A, e7B)
      }
#undef LBBODY
#undef LBISSUE
    }
#undef LSUM

    float a = u15 ? acc : 0.0f;
    a += __shfl_xor(a, 16);
    a += __shfl_xor(a, 32);
    if (lane == 63) lsePart[wv - 2] = a;
  }

  __syncthreads();   // single block-wide sync of the whole kernel

  if (wv == 0) {
    // p = sum_s alpha_{mid-1}(s) * gamma_mid(s); both rescaled to <= 2^45
    float prod = A0 * sG0v[lane] + A1 * sG1v[lane];
    if (lane == 63) prod = fmaf(A2, sG2s, prod);
#pragma unroll
    for (int off = 32; off; off >>= 1) prod += __shfl_xor(prod, off);
    const float p = fmaxf(prod, 1e-37f);   // guard: never log(0) -> inf poisoning
    float loss = ((lsePart[0] + lsePart[1]) + (lsePart[2] + lsePart[3]))
               - LN2 * (__builtin_amdgcn_logf(p) - (float)(ctotA + sCtB));
    if (lab_len > len) loss = 0.0f;  // feasibility mask
    if (lane == 0) atomicAdd(out, loss * (1.0f / 256.0f));
  }
#undef RESCALE45
#undef RENORM3
}

extern "C" void kernel_launch(void* const* d_in, const int* in_sizes, int n_in,
                              void* d_out, int out_size, void* d_ws, size_t ws_size,
                              hipStream_t stream) {
  (void)in_sizes; (void)n_in; (void)out_size; (void)d_ws; (void)ws_size;
  hipMemsetAsync(d_out, 0, sizeof(float), stream);   // d_out is poisoned 0xAA
  ctc_fused<<<dim3(BB), dim3(384), 0, stream>>>(
      (const int*)d_in[0], (const float*)d_in[1], (const int*)d_in[2], (float*)d_out);
}